// Round 11
// baseline (810.285 us; speedup 1.0000x reference)
//
#include <hip/hip_runtime.h>
#include <stdint.h>

#define BQ 4
#define NQ 2048
#define DQ 512
#define YQ 8921
#define YGRP 70                  // y-groups of 128 (32 per wave)
#define NH 8                     // n eighths (256 rows each)
#define NCHQ 16                  // chunks per eighth (16 rows each)
#define NUNITS (YGRP * BQ * NH)  // 2240 = 8*280
#define NLP 140
#define GXOFF 65536              // gx area after 4x16KB buffers
#define L2E 1.44269504088896340736f

typedef __attribute__((ext_vector_type(8))) short bf16x8;
typedef __attribute__((ext_vector_type(4))) float f32x4;

__device__ inline short f2bf(float f) {
  unsigned u = __float_as_uint(f);
  u += 0x7fffu + ((u >> 16) & 1u);   // RTNE
  return (short)(u >> 16);
}

__device__ inline bf16x8 pack8(float4 a, float4 b) {
  bf16x8 h;
  h[0] = f2bf(a.x); h[1] = f2bf(a.y); h[2] = f2bf(a.z); h[3] = f2bf(a.w);
  h[4] = f2bf(b.x); h[5] = f2bf(b.y); h[6] = f2bf(b.z); h[7] = f2bf(b.w);
  return h;
}

__device__ inline void gl_lds16(const void* g, void* l) {
  __builtin_amdgcn_global_load_lds((const __attribute__((address_space(1))) void*)g,
                                   (__attribute__((address_space(3))) void*)l, 16, 0, 0);
}

// ---- prep: gx[b,n] = x[b,n,:].gate_w (fallback path) ----
__global__ __launch_bounds__(256) void prep_gx(const float* __restrict__ x,
                                               const float* __restrict__ gate_w,
                                               float* __restrict__ gx) {
  int rid = blockIdx.x * 4 + (threadIdx.x >> 6);
  int lane = threadIdx.x & 63;
  const float* src = x + (size_t)rid * DQ + lane * 8;
  float4 v0 = *(const float4*)src;
  float4 v1 = *(const float4*)(src + 4);
  const float* gwp = gate_w + lane * 8;
  float s = v0.x * gwp[0] + v0.y * gwp[1] + v0.z * gwp[2] + v0.w * gwp[3]
          + v1.x * gwp[4] + v1.y * gwp[5] + v1.z * gwp[6] + v1.w * gwp[7];
#pragma unroll
  for (int d = 1; d < 64; d <<= 1) s += __shfl_xor(s, d);
  if (lane == 0) gx[rid] = s;
}

// ---- prep: x -> bf16 MFMA-frag order + fused gx dot ----
__global__ __launch_bounds__(256) void prep_xfrag(const float* __restrict__ x,
                                                  const float* __restrict__ gate_w,
                                                  char* __restrict__ ws_x2,
                                                  float* __restrict__ gx) {
  __shared__ float xs[16 * 512];
  int t = blockIdx.x;                       // b*128 + nt
  const float* src = x + ((size_t)t << 13);
  int tid = threadIdx.x;
#pragma unroll
  for (int i = 0; i < 8; ++i)
    *(float4*)(xs + i * 1024 + tid * 4) = *(const float4*)(src + i * 1024 + tid * 4);
  __syncthreads();
  char* dst = ws_x2 + ((size_t)t << 14);
#pragma unroll
  for (int i = 0; i < 4; ++i) {
    int s = i * 256 + tid;
    int l = s & 63, kk = s >> 6;
    int row = l & 15, g = l >> 4;
    const float* p = xs + row * 512 + kk * 32 + g * 8;
    *(bf16x8*)(dst + s * 16) = pack8(*(const float4*)p, *(const float4*)(p + 4));
  }
  // gx: 16 rows x 16 threads, 32 elems each
  int row = tid >> 4, sub = tid & 15;
  const float* xr = xs + row * 512 + sub * 32;
  const float* gw = gate_w + sub * 32;
  float s = 0.f;
#pragma unroll
  for (int i = 0; i < 8; ++i) {
    float4 a = *(const float4*)(xr + i * 4);
    float4 g = *(const float4*)(gw + i * 4);
    s += a.x * g.x + a.y * g.y + a.z * g.z + a.w * g.w;
  }
  s += __shfl_xor(s, 1); s += __shfl_xor(s, 2);
  s += __shfl_xor(s, 4); s += __shfl_xor(s, 8);
  if (sub == 0) gx[t * 16 + row] = s;
}

// ---- fused partial: 32y/wave (6 W-frag sets, ~430 regs), 1 wave/SIMD ----
// unit = (b, yg, nh), nh innermost. Wave w owns y [yg*128 + w*32, +32).
// LDS reads halved vs 16y/wave: each ds_read feeds 6 MFMAs.
template<bool FULL>
__global__ __launch_bounds__(256, 1) void fused_kernel(
    const float* __restrict__ x, const char* __restrict__ ws_x2,
    const float* __restrict__ Uw, const float* __restrict__ Gw,
    const float* __restrict__ Fw, const float* __restrict__ gx,
    float4* __restrict__ ws_state) {
  extern __shared__ char smem[];
  const int tid = threadIdx.x, l = tid & 63, w = tid >> 6;
  const int lr = l & 15, lg4 = l >> 4;
  int u = (blockIdx.x & 7) * (NUNITS / 8) + (blockIdx.x >> 3);
  const int b = u / (YGRP * NH);
  const int r0 = u % (YGRP * NH);
  const int yg = r0 / NH, nh = r0 % NH;
  const int ybase = yg * 128 + w * 32;
  const int nbase = nh * (NQ / NH);

  // ---- W fragments: 2 y-tiles x 3 branches x 16 k-frags = 384 regs ----
  bf16x8 wU[2][16], wG[2][16], wF[2][16];
#pragma unroll
  for (int t = 0; t < 2; ++t) {
    int y = ybase + t * 16 + lr; if (y >= YQ) y = YQ - 1;
    const float* pu = Uw + (size_t)y * DQ + lg4 * 8;
    const float* pg = Gw + (size_t)y * DQ + lg4 * 8;
    const float* pf = Fw + (size_t)y * DQ + lg4 * 8;
#pragma unroll
    for (int kk = 0; kk < 16; ++kk) {
      wU[t][kk] = pack8(*(const float4*)(pu + kk * 32), *(const float4*)(pu + kk * 32 + 4));
      wG[t][kk] = pack8(*(const float4*)(pg + kk * 32), *(const float4*)(pg + kk * 32 + 4));
      wF[t][kk] = pack8(*(const float4*)(pf + kk * 32), *(const float4*)(pf + kk * 32 + 4));
    }
  }

  float lU0 = 0.f, aU0 = 0.f, lG0 = 0.f, aG0 = 0.f;
  float lU1 = 0.f, aU1 = 0.f, lG1 = 0.f, aG1 = 0.f;

  if constexpr (FULL) {
    // gx eighth (256 floats) into LDS
    ((float*)(smem + GXOFF))[tid] = gx[b * NQ + nbase + tid];
    __syncthreads();                 // drains vmcnt: clean baseline

    const char* xb = ws_x2 + (((size_t)(b * 128 + nh * NCHQ)) << 14);
    auto stage = [&](int c) {
      const char* src = xb + ((size_t)c << 14);
      char* lb = smem + (c & 3) * 16384;
#pragma unroll
      for (int j = 0; j < 4; ++j) {
        int s = w * 4 + j;
        gl_lds16(src + s * 1024 + l * 16, lb + s * 1024);
      }
    };
    auto compute = [&](int c) {
      const char* ab = smem + (c & 3) * 16384 + l * 16;
      f32x4 sU0 = {0.f, 0.f, 0.f, 0.f}, sG0 = sU0, sF0 = sU0;
      f32x4 sU1 = sU0, sG1 = sU0, sF1 = sU0;
      __builtin_amdgcn_s_setprio(1);
#pragma unroll
      for (int kk = 0; kk < 16; ++kk) {
        bf16x8 a = *(const bf16x8*)(ab + kk * 1024);
        sU0 = __builtin_amdgcn_mfma_f32_16x16x32_bf16(a, wU[0][kk], sU0, 0, 0, 0);
        sG0 = __builtin_amdgcn_mfma_f32_16x16x32_bf16(a, wG[0][kk], sG0, 0, 0, 0);
        sF0 = __builtin_amdgcn_mfma_f32_16x16x32_bf16(a, wF[0][kk], sF0, 0, 0, 0);
        sU1 = __builtin_amdgcn_mfma_f32_16x16x32_bf16(a, wU[1][kk], sU1, 0, 0, 0);
        sG1 = __builtin_amdgcn_mfma_f32_16x16x32_bf16(a, wG[1][kk], sG1, 0, 0, 0);
        sF1 = __builtin_amdgcn_mfma_f32_16x16x32_bf16(a, wF[1][kk], sF1, 0, 0, 0);
      }
      __builtin_amdgcn_s_setprio(0);
      float4 gxv = *(const float4*)(smem + GXOFF + c * 64 + lg4 * 16);
      float gv[4] = {gxv.x, gxv.y, gxv.z, gxv.w};
#pragma unroll
      for (int r = 0; r < 4; ++r) {
        float e;
        e = __builtin_amdgcn_exp2f(sU0[r] * L2E); lU0 += e; aU0 = fmaf(e, sF0[r], aU0);
        e = __builtin_amdgcn_exp2f(sG0[r] * L2E); lG0 += e; aG0 = fmaf(e, gv[r], aG0);
        e = __builtin_amdgcn_exp2f(sU1[r] * L2E); lU1 += e; aU1 = fmaf(e, sF1[r], aU1);
        e = __builtin_amdgcn_exp2f(sG1[r] * L2E); lG1 += e; aG1 = fmaf(e, gv[r], aG1);
      }
    };

    stage(0); stage(1);              // outstanding {0,1} (8 instr/wave)
    asm volatile("s_waitcnt vmcnt(4)" ::: "memory");   // chunk0 done (this wave)
    __builtin_amdgcn_s_barrier();                      // chunk0 done (all waves)

#pragma unroll 1
    for (int c = 0; c < NCHQ; ++c) {
      if (c + 2 < NCHQ) stage(c + 2);                  // outstanding {c+1, c+2}
      compute(c);
      if (c + 1 < NCHQ) {
        if (c + 2 < NCHQ) asm volatile("s_waitcnt vmcnt(4)" ::: "memory"); // c+1 done
        else              asm volatile("s_waitcnt vmcnt(0)" ::: "memory");
        __builtin_amdgcn_sched_barrier(0);
        __builtin_amdgcn_s_barrier();                  // c+1 ready for all waves
      }
    }
  } else {
    const float* gxb = gx + b * NQ + nbase + lg4 * 4;
    for (int c = 0; c < NCHQ; ++c) {
      __syncthreads();
#pragma unroll
      for (int j = 0; j < 4; ++j) {
        int slot = j * 256 + tid;                  // 1024 slots * 16B = 16KB
        int kk = slot >> 6, l2 = slot & 63;
        int row = l2 & 15, g4 = l2 >> 4;
        const float* g = x + ((size_t)(b * NQ + nbase + c * 16 + row)) * DQ
                       + kk * 32 + g4 * 8;
        *(bf16x8*)(smem + slot * 16) = pack8(*(const float4*)g, *(const float4*)(g + 4));
      }
      __syncthreads();
      const char* ab = smem + l * 16;
      f32x4 sU0 = {0.f, 0.f, 0.f, 0.f}, sG0 = sU0, sF0 = sU0;
      f32x4 sU1 = sU0, sG1 = sU0, sF1 = sU0;
#pragma unroll
      for (int kk = 0; kk < 16; ++kk) {
        bf16x8 a = *(const bf16x8*)(ab + kk * 1024);
        sU0 = __builtin_amdgcn_mfma_f32_16x16x32_bf16(a, wU[0][kk], sU0, 0, 0, 0);
        sG0 = __builtin_amdgcn_mfma_f32_16x16x32_bf16(a, wG[0][kk], sG0, 0, 0, 0);
        sF0 = __builtin_amdgcn_mfma_f32_16x16x32_bf16(a, wF[0][kk], sF0, 0, 0, 0);
        sU1 = __builtin_amdgcn_mfma_f32_16x16x32_bf16(a, wU[1][kk], sU1, 0, 0, 0);
        sG1 = __builtin_amdgcn_mfma_f32_16x16x32_bf16(a, wG[1][kk], sG1, 0, 0, 0);
        sF1 = __builtin_amdgcn_mfma_f32_16x16x32_bf16(a, wF[1][kk], sF1, 0, 0, 0);
      }
      float4 gxv = *(const float4*)(gxb + c * 16);
      float gv[4] = {gxv.x, gxv.y, gxv.z, gxv.w};
#pragma unroll
      for (int r = 0; r < 4; ++r) {
        float e;
        e = __builtin_amdgcn_exp2f(sU0[r] * L2E); lU0 += e; aU0 = fmaf(e, sF0[r], aU0);
        e = __builtin_amdgcn_exp2f(sG0[r] * L2E); lG0 += e; aG0 = fmaf(e, gv[r], aG0);
        e = __builtin_amdgcn_exp2f(sU1[r] * L2E); lU1 += e; aU1 = fmaf(e, sF1[r], aU1);
        e = __builtin_amdgcn_exp2f(sG1[r] * L2E); lG1 += e; aG1 = fmaf(e, gv[r], aG1);
      }
    }
  }

  // ---- additive lane-group merge ----
#pragma unroll
  for (int d = 16; d < 64; d <<= 1) {
    lU0 += __shfl_xor(lU0, d); aU0 += __shfl_xor(aU0, d);
    lG0 += __shfl_xor(lG0, d); aG0 += __shfl_xor(aG0, d);
    lU1 += __shfl_xor(lU1, d); aU1 += __shfl_xor(aU1, d);
    lG1 += __shfl_xor(lG1, d); aG1 += __shfl_xor(aG1, d);
  }

  if (lg4 == 0) {
    int y0 = ybase + lr;
    if (y0 < YQ) {
      float4 st; st.x = lU0; st.y = aU0; st.z = lG0; st.w = aG0;
      ws_state[(size_t)(b * NH + nh) * YQ + y0] = st;
    }
    int y1 = ybase + 16 + lr;
    if (y1 < YQ) {
      float4 st; st.x = lU1; st.y = aU1; st.z = lG1; st.w = aG1;
      ws_state[(size_t)(b * NH + nh) * YQ + y1] = st;
    }
  }
}

// ---- merge eighths + epilogue + loss partials ----
__global__ __launch_bounds__(256) void merge_kernel(
    const float4* __restrict__ ws_state, const float* __restrict__ fb,
    const float* __restrict__ gate_b, const float* __restrict__ yflow,
    const float* __restrict__ target, float* __restrict__ out_y,
    float* __restrict__ loss_part) {
  __shared__ float sb[256];
  int t = blockIdx.x * 256 + threadIdx.x;
  float lt = 0.f;
  if (t < BQ * YQ) {
    int b = t / YQ, y = t % YQ;
    float lU = 0.f, aU = 0.f, lG = 0.f, aG = 0.f;
#pragma unroll
    for (int nh = 0; nh < NH; ++nh) {
      float4 s = ws_state[(size_t)(b * NH + nh) * YQ + y];
      lU += s.x; aU += s.y; lG += s.z; aG += s.w;
    }
    float gate = tanhf(aG / lG + gate_b[0]);
    float yv = aU / lU + fb[y] + yflow[t] * gate;
    out_y[t] = yv;
    float tg = target[t];
    lt = fmaxf(yv, 0.f) + log1pf(__expf(-fabsf(yv))) - yv * tg;
  }
  sb[threadIdx.x] = lt;
  __syncthreads();
  for (int st = 128; st > 0; st >>= 1) {
    if (threadIdx.x < st) sb[threadIdx.x] += sb[threadIdx.x + st];
    __syncthreads();
  }
  if (threadIdx.x == 0) loss_part[blockIdx.x] = sb[0];
}

__global__ __launch_bounds__(256) void loss_kernel(const float* __restrict__ lp,
                                                   float* __restrict__ out) {
  __shared__ float sb[256];
  float s = (threadIdx.x < NLP) ? lp[threadIdx.x] : 0.f;
  sb[threadIdx.x] = s;
  __syncthreads();
  for (int st = 128; st > 0; st >>= 1) {
    if (threadIdx.x < st) sb[threadIdx.x] += sb[threadIdx.x + st];
    __syncthreads();
  }
  if (threadIdx.x == 0) out[BQ * YQ] = sb[0] / (float)(BQ * YQ);
}

extern "C" void kernel_launch(void* const* d_in, const int* in_sizes, int n_in,
                              void* d_out, int out_size, void* d_ws, size_t ws_size,
                              hipStream_t stream) {
  const float* x      = (const float*)d_in[0];
  const float* target = (const float*)d_in[1];
  const float* yflow  = (const float*)d_in[2];
  const float* Uw     = (const float*)d_in[3];
  const float* Gw     = (const float*)d_in[4];
  const float* Fw     = (const float*)d_in[5];
  const float* fb     = (const float*)d_in[6];
  const float* gw     = (const float*)d_in[7];
  const float* gb     = (const float*)d_in[8];
  float* out = (float*)d_out;
  char* ws = (char*)d_ws;

  const size_t xbytes  = (size_t)BQ * NQ * DQ * 2;          // 8 MB frag-ordered
  const size_t gxbytes = (size_t)BQ * NQ * 4;               // 32 KB
  const size_t stbytes = (size_t)BQ * NH * YQ * 16;         // ~4.6 MB
  const size_t lpbytes = (size_t)NLP * 4;
  const bool full = ws_size >= xbytes + gxbytes + stbytes + lpbytes;

  char* ws_x2; float* gxp; float4* stp; float* lp;
  if (full) {
    ws_x2 = ws;
    gxp = (float*)(ws + xbytes);
    stp = (float4*)(ws + xbytes + gxbytes);
    lp  = (float*)(ws + xbytes + gxbytes + stbytes);
  } else {
    ws_x2 = nullptr;
    gxp = (float*)ws;
    stp = (float4*)(ws + gxbytes);
    lp  = (float*)(ws + gxbytes + stbytes);
  }

  (void)hipFuncSetAttribute(reinterpret_cast<const void*>(&fused_kernel<true>),
                            hipFuncAttributeMaxDynamicSharedMemorySize, 66560);
  (void)hipFuncSetAttribute(reinterpret_cast<const void*>(&fused_kernel<false>),
                            hipFuncAttributeMaxDynamicSharedMemorySize, 16384);

  if (full) {
    prep_xfrag<<<dim3(BQ * 128), 256, 0, stream>>>(x, gw, ws_x2, gxp);
    fused_kernel<true ><<<dim3(NUNITS), 256, 66560, stream>>>(
        x, ws_x2, Uw, Gw, Fw, gxp, stp);
  } else {
    prep_gx<<<dim3(2048), 256, 0, stream>>>(x, gw, gxp);
    fused_kernel<false><<<dim3(NUNITS), 256, 16384, stream>>>(
        x, ws_x2, Uw, Gw, Fw, gxp, stp);
  }
  merge_kernel<<<dim3(NLP), 256, 0, stream>>>(stp, fb, gb, yflow, target, out, lp);
  loss_kernel<<<1, 256, 0, stream>>>(lp, out);
}

// Round 12
// 393.594 us; speedup vs baseline: 2.0587x; 2.0587x over previous
//
#include <hip/hip_runtime.h>
#include <stdint.h>

#define BQ 4
#define NQ 2048
#define DQ 512
#define YQ 8921
#define YGRP 140                 // y-groups of 64
#define NH 4                     // n quarters (512 rows each)
#define NCHQ 16                  // chunks per quarter (32 rows each)
#define NUNITS (YGRP * BQ * NH)  // 2240 = 8*280
#define NLP 140
#define GXOFF 131072             // gx after 4x32KB buffers
#define L2E 1.44269504088896340736f

typedef __attribute__((ext_vector_type(8))) short bf16x8;
typedef __attribute__((ext_vector_type(4))) float f32x4;

__device__ inline short f2bf(float f) {
  unsigned u = __float_as_uint(f);
  u += 0x7fffu + ((u >> 16) & 1u);   // RTNE
  return (short)(u >> 16);
}

__device__ inline bf16x8 pack8(float4 a, float4 b) {
  bf16x8 h;
  h[0] = f2bf(a.x); h[1] = f2bf(a.y); h[2] = f2bf(a.z); h[3] = f2bf(a.w);
  h[4] = f2bf(b.x); h[5] = f2bf(b.y); h[6] = f2bf(b.z); h[7] = f2bf(b.w);
  return h;
}

__device__ inline void gl_lds16(const void* g, void* l) {
  __builtin_amdgcn_global_load_lds((const __attribute__((address_space(1))) void*)g,
                                   (__attribute__((address_space(3))) void*)l, 16, 0, 0);
}

// ---- prep: gx[b,n] = x[b,n,:].gate_w (fallback path) ----
__global__ __launch_bounds__(256) void prep_gx(const float* __restrict__ x,
                                               const float* __restrict__ gate_w,
                                               float* __restrict__ gx) {
  int rid = blockIdx.x * 4 + (threadIdx.x >> 6);
  int lane = threadIdx.x & 63;
  const float* src = x + (size_t)rid * DQ + lane * 8;
  float4 v0 = *(const float4*)src;
  float4 v1 = *(const float4*)(src + 4);
  const float* gwp = gate_w + lane * 8;
  float s = v0.x * gwp[0] + v0.y * gwp[1] + v0.z * gwp[2] + v0.w * gwp[3]
          + v1.x * gwp[4] + v1.y * gwp[5] + v1.z * gwp[6] + v1.w * gwp[7];
#pragma unroll
  for (int d = 1; d < 64; d <<= 1) s += __shfl_xor(s, d);
  if (lane == 0) gx[rid] = s;
}

// ---- prep: x -> bf16 MFMA-frag order + fused gx dot ----
__global__ __launch_bounds__(256) void prep_xfrag(const float* __restrict__ x,
                                                  const float* __restrict__ gate_w,
                                                  char* __restrict__ ws_x2,
                                                  float* __restrict__ gx) {
  __shared__ float xs[16 * 512];
  int t = blockIdx.x;                       // b*128 + nt
  const float* src = x + ((size_t)t << 13);
  int tid = threadIdx.x;
#pragma unroll
  for (int i = 0; i < 8; ++i)
    *(float4*)(xs + i * 1024 + tid * 4) = *(const float4*)(src + i * 1024 + tid * 4);
  __syncthreads();
  char* dst = ws_x2 + ((size_t)t << 14);
#pragma unroll
  for (int i = 0; i < 4; ++i) {
    int s = i * 256 + tid;
    int l = s & 63, kk = s >> 6;
    int row = l & 15, g = l >> 4;
    const float* p = xs + row * 512 + kk * 32 + g * 8;
    *(bf16x8*)(dst + s * 16) = pack8(*(const float4*)p, *(const float4*)(p + 4));
  }
  // gx: 16 rows x 16 threads, 32 elems each
  int row = tid >> 4, sub = tid & 15;
  const float* xr = xs + row * 512 + sub * 32;
  const float* gw = gate_w + sub * 32;
  float s = 0.f;
#pragma unroll
  for (int i = 0; i < 8; ++i) {
    float4 a = *(const float4*)(xr + i * 4);
    float4 g = *(const float4*)(gw + i * 4);
    s += a.x * g.x + a.y * g.y + a.z * g.z + a.w * g.w;
  }
  s += __shfl_xor(s, 1); s += __shfl_xor(s, 2);
  s += __shfl_xor(s, 4); s += __shfl_xor(s, 8);
  if (sub == 0) gx[t * 16 + row] = s;
}

// ---- fused partial: 1 wave/SIMD, explicit A-frag reg double-buffer ----
// unit = (b, yg, nh), nh innermost. 4 waves/block, 1 block/CU (133KB LDS).
// Wave w owns y [yg*64 + w*16, +16). Reads of next half issue as independent
// ops under current half's 48 MFMAs (structural ILP, no TLP needed).
template<bool FULL>
__global__ __launch_bounds__(256, 1) void fused_kernel(
    const float* __restrict__ x, const char* __restrict__ ws_x2,
    const float* __restrict__ Uw, const float* __restrict__ Gw,
    const float* __restrict__ Fw, const float* __restrict__ gx,
    float4* __restrict__ ws_state) {
  extern __shared__ char smem[];
  const int tid = threadIdx.x, l = tid & 63, w = tid >> 6;
  const int lr = l & 15, lg4 = l >> 4;
  int u = (blockIdx.x & 7) * (NUNITS / 8) + (blockIdx.x >> 3);
  const int b = u / (YGRP * NH);
  const int r0 = u % (YGRP * NH);
  const int yg = r0 / NH, nh = r0 % NH;
  const int ybase = yg * 64 + w * 16;
  const int nbase = nh * (NQ / NH);

  // ---- W fragments: 3 branches x 16 k-frags = 192 regs (from f32 global) ----
  bf16x8 wU[16], wG[16], wF[16];
  {
    int y = ybase + lr; if (y >= YQ) y = YQ - 1;
    const float* pu = Uw + (size_t)y * DQ + lg4 * 8;
    const float* pg = Gw + (size_t)y * DQ + lg4 * 8;
    const float* pf = Fw + (size_t)y * DQ + lg4 * 8;
#pragma unroll
    for (int kk = 0; kk < 16; ++kk) {
      wU[kk] = pack8(*(const float4*)(pu + kk * 32), *(const float4*)(pu + kk * 32 + 4));
      wG[kk] = pack8(*(const float4*)(pg + kk * 32), *(const float4*)(pg + kk * 32 + 4));
      wF[kk] = pack8(*(const float4*)(pf + kk * 32), *(const float4*)(pf + kk * 32 + 4));
    }
  }

  float lU = 0.f, aU = 0.f, lG = 0.f, aG = 0.f;

  if constexpr (FULL) {
    // gx quarter (512 floats) into LDS
    *(float2*)(smem + GXOFF + tid * 8) = *(const float2*)(gx + b * NQ + nbase + tid * 2);
    __syncthreads();                 // drains vmcnt: clean baseline

    const char* xb = ws_x2 + (((size_t)(b * 128 + nh * 32)) << 14);
    auto stage = [&](int c) {        // 32KB chunk = two 16KB frag tiles; 8 instr/wave
      char* lb = smem + (c & 3) * 32768;
#pragma unroll
      for (int j = 0; j < 8; ++j) {
        int s = w * 8 + j;           // 0..31: t2 = s>>4, kk = s&15
        gl_lds16(xb + (((size_t)(2 * c + (s >> 4))) << 14) + (s & 15) * 1024 + l * 16,
                 lb + s * 1024);
      }
    };
    auto read16 = [&](int c, int t2, bf16x8* A) {
      const char* ab = smem + (c & 3) * 32768 + t2 * 16384 + l * 16;
#pragma unroll
      for (int kk = 0; kk < 16; ++kk) A[kk] = *(const bf16x8*)(ab + kk * 1024);
    };
    auto mfma48 = [&](const bf16x8* A, int c, int t2) {
      f32x4 sU = {0.f, 0.f, 0.f, 0.f}, sG = sU, sF = sU;
      __builtin_amdgcn_s_setprio(1);
#pragma unroll
      for (int kk = 0; kk < 16; ++kk) {
        sU = __builtin_amdgcn_mfma_f32_16x16x32_bf16(A[kk], wU[kk], sU, 0, 0, 0);
        sG = __builtin_amdgcn_mfma_f32_16x16x32_bf16(A[kk], wG[kk], sG, 0, 0, 0);
        sF = __builtin_amdgcn_mfma_f32_16x16x32_bf16(A[kk], wF[kk], sF, 0, 0, 0);
      }
      __builtin_amdgcn_s_setprio(0);
      float4 gxv = *(const float4*)(smem + GXOFF + c * 128 + t2 * 64 + lg4 * 16);
      float gv[4] = {gxv.x, gxv.y, gxv.z, gxv.w};
#pragma unroll
      for (int r = 0; r < 4; ++r) {
        float eu = __builtin_amdgcn_exp2f(sU[r] * L2E);
        lU += eu; aU = fmaf(eu, sF[r], aU);
        float eg = __builtin_amdgcn_exp2f(sG[r] * L2E);
        lG += eg; aG = fmaf(eg, gv[r], aG);
      }
    };

    bf16x8 Aa[16], Ab[16];
    stage(0); stage(1);                                // outstanding {0:8, 1:8}
    asm volatile("s_waitcnt vmcnt(8)" ::: "memory");   // chunk0 done (this wave)
    __builtin_amdgcn_s_barrier();                      // chunk0 done (all waves)
    read16(0, 0, Aa);

#pragma unroll 1
    for (int c = 0; c < NCHQ - 1; ++c) {
      if (c + 2 < NCHQ) stage(c + 2);                  // outstanding {c+1, c+2}
      read16(c, 1, Ab);                                // issues under mfma below
      mfma48(Aa, c, 0);
      if (c + 2 < NCHQ) asm volatile("s_waitcnt vmcnt(8)" ::: "memory"); // c+1 done
      else              asm volatile("s_waitcnt vmcnt(0)" ::: "memory");
      __builtin_amdgcn_sched_barrier(0);
      __builtin_amdgcn_s_barrier();                    // c+1 ready (all waves)
      read16(c + 1, 0, Aa);                            // issues under mfma below
      mfma48(Ab, c, 1);
    }
    read16(NCHQ - 1, 1, Ab);
    mfma48(Aa, NCHQ - 1, 0);
    mfma48(Ab, NCHQ - 1, 1);
  } else {
    const float* gxb = gx + b * NQ + nbase + lg4 * 4;
    for (int c = 0; c < NCHQ; ++c) {
      __syncthreads();
#pragma unroll
      for (int j = 0; j < 8; ++j) {
        int slot = j * 256 + tid;                  // 2048 slots * 16B = 32KB
        int t2 = slot >> 10, kk = (slot >> 6) & 15, l2 = slot & 63;
        int row = t2 * 16 + (l2 & 15), g4 = l2 >> 4;
        const float* g = x + ((size_t)(b * NQ + nbase + c * 32 + row)) * DQ
                       + kk * 32 + g4 * 8;
        *(bf16x8*)(smem + slot * 16) = pack8(*(const float4*)g, *(const float4*)(g + 4));
      }
      __syncthreads();
#pragma unroll
      for (int t2 = 0; t2 < 2; ++t2) {
        const char* ab = smem + t2 * 16384 + l * 16;
        f32x4 sU = {0.f, 0.f, 0.f, 0.f}, sG = sU, sF = sU;
#pragma unroll
        for (int kk = 0; kk < 16; ++kk) {
          bf16x8 a = *(const bf16x8*)(ab + kk * 1024);
          sU = __builtin_amdgcn_mfma_f32_16x16x32_bf16(a, wU[kk], sU, 0, 0, 0);
          sG = __builtin_amdgcn_mfma_f32_16x16x32_bf16(a, wG[kk], sG, 0, 0, 0);
          sF = __builtin_amdgcn_mfma_f32_16x16x32_bf16(a, wF[kk], sF, 0, 0, 0);
        }
        float4 gxv = *(const float4*)(gxb + c * 32 + t2 * 16);
        float gv[4] = {gxv.x, gxv.y, gxv.z, gxv.w};
#pragma unroll
        for (int r = 0; r < 4; ++r) {
          float eu = __builtin_amdgcn_exp2f(sU[r] * L2E);
          lU += eu; aU = fmaf(eu, sF[r], aU);
          float eg = __builtin_amdgcn_exp2f(sG[r] * L2E);
          lG += eg; aG = fmaf(eg, gv[r], aG);
        }
      }
    }
  }

  // ---- additive lane-group merge ----
#pragma unroll
  for (int d = 16; d < 64; d <<= 1) {
    lU += __shfl_xor(lU, d); aU += __shfl_xor(aU, d);
    lG += __shfl_xor(lG, d); aG += __shfl_xor(aG, d);
  }

  int y = ybase + lr;
  if (lg4 == 0 && y < YQ) {
    float4 st; st.x = lU; st.y = aU; st.z = lG; st.w = aG;
    ws_state[(size_t)(b * NH + nh) * YQ + y] = st;
  }
}

// ---- merge quarters + epilogue + loss partials ----
__global__ __launch_bounds__(256) void merge_kernel(
    const float4* __restrict__ ws_state, const float* __restrict__ fb,
    const float* __restrict__ gate_b, const float* __restrict__ yflow,
    const float* __restrict__ target, float* __restrict__ out_y,
    float* __restrict__ loss_part) {
  __shared__ float sb[256];
  int t = blockIdx.x * 256 + threadIdx.x;
  float lt = 0.f;
  if (t < BQ * YQ) {
    int b = t / YQ, y = t % YQ;
    float lU = 0.f, aU = 0.f, lG = 0.f, aG = 0.f;
#pragma unroll
    for (int nh = 0; nh < NH; ++nh) {
      float4 s = ws_state[(size_t)(b * NH + nh) * YQ + y];
      lU += s.x; aU += s.y; lG += s.z; aG += s.w;
    }
    float gate = tanhf(aG / lG + gate_b[0]);
    float yv = aU / lU + fb[y] + yflow[t] * gate;
    out_y[t] = yv;
    float tg = target[t];
    lt = fmaxf(yv, 0.f) + log1pf(__expf(-fabsf(yv))) - yv * tg;
  }
  sb[threadIdx.x] = lt;
  __syncthreads();
  for (int st = 128; st > 0; st >>= 1) {
    if (threadIdx.x < st) sb[threadIdx.x] += sb[threadIdx.x + st];
    __syncthreads();
  }
  if (threadIdx.x == 0) loss_part[blockIdx.x] = sb[0];
}

__global__ __launch_bounds__(256) void loss_kernel(const float* __restrict__ lp,
                                                   float* __restrict__ out) {
  __shared__ float sb[256];
  float s = (threadIdx.x < NLP) ? lp[threadIdx.x] : 0.f;
  sb[threadIdx.x] = s;
  __syncthreads();
  for (int st = 128; st > 0; st >>= 1) {
    if (threadIdx.x < st) sb[threadIdx.x] += sb[threadIdx.x + st];
    __syncthreads();
  }
  if (threadIdx.x == 0) out[BQ * YQ] = sb[0] / (float)(BQ * YQ);
}

extern "C" void kernel_launch(void* const* d_in, const int* in_sizes, int n_in,
                              void* d_out, int out_size, void* d_ws, size_t ws_size,
                              hipStream_t stream) {
  const float* x      = (const float*)d_in[0];
  const float* target = (const float*)d_in[1];
  const float* yflow  = (const float*)d_in[2];
  const float* Uw     = (const float*)d_in[3];
  const float* Gw     = (const float*)d_in[4];
  const float* Fw     = (const float*)d_in[5];
  const float* fb     = (const float*)d_in[6];
  const float* gw     = (const float*)d_in[7];
  const float* gb     = (const float*)d_in[8];
  float* out = (float*)d_out;
  char* ws = (char*)d_ws;

  const size_t xbytes  = (size_t)BQ * NQ * DQ * 2;          // 8 MB frag-ordered
  const size_t gxbytes = (size_t)BQ * NQ * 4;               // 32 KB
  const size_t stbytes = (size_t)BQ * NH * YQ * 16;         // ~2.3 MB
  const size_t lpbytes = (size_t)NLP * 4;
  const bool full = ws_size >= xbytes + gxbytes + stbytes + lpbytes;

  char* ws_x2; float* gxp; float4* stp; float* lp;
  if (full) {
    ws_x2 = ws;
    gxp = (float*)(ws + xbytes);
    stp = (float4*)(ws + xbytes + gxbytes);
    lp  = (float*)(ws + xbytes + gxbytes + stbytes);
  } else {
    ws_x2 = nullptr;
    gxp = (float*)ws;
    stp = (float4*)(ws + gxbytes);
    lp  = (float*)(ws + gxbytes + stbytes);
  }

  (void)hipFuncSetAttribute(reinterpret_cast<const void*>(&fused_kernel<true>),
                            hipFuncAttributeMaxDynamicSharedMemorySize, 133120);
  (void)hipFuncSetAttribute(reinterpret_cast<const void*>(&fused_kernel<false>),
                            hipFuncAttributeMaxDynamicSharedMemorySize, 32768);

  if (full) {
    prep_xfrag<<<dim3(BQ * 128), 256, 0, stream>>>(x, gw, ws_x2, gxp);
    fused_kernel<true ><<<dim3(NUNITS), 256, 133120, stream>>>(
        x, ws_x2, Uw, Gw, Fw, gxp, stp);
  } else {
    prep_gx<<<dim3(2048), 256, 0, stream>>>(x, gw, gxp);
    fused_kernel<false><<<dim3(NUNITS), 256, 32768, stream>>>(
        x, ws_x2, Uw, Gw, Fw, gxp, stp);
  }
  merge_kernel<<<dim3(NLP), 256, 0, stream>>>(stp, fb, gb, yflow, target, out, lp);
  loss_kernel<<<1, 256, 0, stream>>>(lp, out);
}

// Round 13
// 219.157 us; speedup vs baseline: 3.6973x; 1.7959x over previous
//
#include <hip/hip_runtime.h>
#include <stdint.h>

#define BQ 4
#define NQ 2048
#define DQ 512
#define YQ 8921
#define YGRP 140                 // y-groups of 64
#define NH 4                     // n quarters (512 rows each)
#define NCHQ 32                  // chunks per quarter (16 rows each)
#define NUNITS (YGRP * BQ * NH)  // 2240 = 8*280
#define NLP 140
#define GXOFF 65536              // gx area after 4x16KB buffers
#define L2E 1.44269504088896340736f

typedef __attribute__((ext_vector_type(8))) short bf16x8;
typedef __attribute__((ext_vector_type(4))) float f32x4;

__device__ inline short f2bf(float f) {
  unsigned u = __float_as_uint(f);
  u += 0x7fffu + ((u >> 16) & 1u);   // RTNE
  return (short)(u >> 16);
}

__device__ inline bf16x8 pack8(float4 a, float4 b) {
  bf16x8 h;
  h[0] = f2bf(a.x); h[1] = f2bf(a.y); h[2] = f2bf(a.z); h[3] = f2bf(a.w);
  h[4] = f2bf(b.x); h[5] = f2bf(b.y); h[6] = f2bf(b.z); h[7] = f2bf(b.w);
  return h;
}

__device__ inline void gl_lds16(const void* g, void* l) {
  __builtin_amdgcn_global_load_lds((const __attribute__((address_space(1))) void*)g,
                                   (__attribute__((address_space(3))) void*)l, 16, 0, 0);
}

// ---- prep: gx[b,n] = x[b,n,:].gate_w (fallback path only) ----
__global__ __launch_bounds__(256) void prep_gx(const float* __restrict__ x,
                                               const float* __restrict__ gate_w,
                                               float* __restrict__ gx) {
  int rid = blockIdx.x * 4 + (threadIdx.x >> 6);
  int lane = threadIdx.x & 63;
  const float* src = x + (size_t)rid * DQ + lane * 8;
  float4 v0 = *(const float4*)src;
  float4 v1 = *(const float4*)(src + 4);
  const float* gwp = gate_w + lane * 8;
  float s = v0.x * gwp[0] + v0.y * gwp[1] + v0.z * gwp[2] + v0.w * gwp[3]
          + v1.x * gwp[4] + v1.y * gwp[5] + v1.z * gwp[6] + v1.w * gwp[7];
#pragma unroll
  for (int d = 1; d < 64; d <<= 1) s += __shfl_xor(s, d);
  if (lane == 0) gx[rid] = s;
}

// ---- prep: x -> bf16 MFMA-frag order + fused gx dot ----
__global__ __launch_bounds__(256) void prep_xfrag(const float* __restrict__ x,
                                                  const float* __restrict__ gate_w,
                                                  char* __restrict__ ws_x2,
                                                  float* __restrict__ gx) {
  __shared__ float xs[16 * 512];
  int t = blockIdx.x;                       // b*128 + nt
  const float* src = x + ((size_t)t << 13);
  int tid = threadIdx.x;
#pragma unroll
  for (int i = 0; i < 8; ++i)
    *(float4*)(xs + i * 1024 + tid * 4) = *(const float4*)(src + i * 1024 + tid * 4);
  __syncthreads();
  char* dst = ws_x2 + ((size_t)t << 14);
#pragma unroll
  for (int i = 0; i < 4; ++i) {
    int s = i * 256 + tid;
    int l = s & 63, kk = s >> 6;
    int row = l & 15, g = l >> 4;
    const float* p = xs + row * 512 + kk * 32 + g * 8;
    *(bf16x8*)(dst + s * 16) = pack8(*(const float4*)p, *(const float4*)(p + 4));
  }
  // gx: 16 rows x 16 threads, 32 elems each
  int row = tid >> 4, sub = tid & 15;
  const float* xr = xs + row * 512 + sub * 32;
  const float* gw = gate_w + sub * 32;
  float s = 0.f;
#pragma unroll
  for (int i = 0; i < 8; ++i) {
    float4 a = *(const float4*)(xr + i * 4);
    float4 g = *(const float4*)(gw + i * 4);
    s += a.x * g.x + a.y * g.y + a.z * g.z + a.w * g.w;
  }
  s += __shfl_xor(s, 1); s += __shfl_xor(s, 2);
  s += __shfl_xor(s, 4); s += __shfl_xor(s, 8);
  if (sub == 0) gx[t * 16 + row] = s;
}

// ---- prep: W (U,Ug,F) f32 -> bf16 row-major [3][YQ][512] ----
__global__ __launch_bounds__(256) void prep_w(const float* __restrict__ Uw,
                                              const float* __restrict__ Gw,
                                              const float* __restrict__ Fw,
                                              char* __restrict__ ws_w) {
  int rid = blockIdx.x * 4 + (threadIdx.x >> 6);
  if (rid >= 3 * YQ) return;
  int lane = threadIdx.x & 63;
  int mat = rid / YQ, y = rid % YQ;
  const float* src = (mat == 0 ? Uw : (mat == 1 ? Gw : Fw)) + (size_t)y * DQ + lane * 8;
  *(bf16x8*)(ws_w + (size_t)rid * 1024 + lane * 16) =
      pack8(*(const float4*)src, *(const float4*)(src + 4));
}

// ---- fused partial: R10 structure + anti-phase start skew for co-resident blocks ----
template<bool FULL>
__global__ __launch_bounds__(256, 2) void fused_kernel(
    const float* __restrict__ x, const char* __restrict__ ws_x2,
    const char* __restrict__ ws_w,
    const float* __restrict__ Uw, const float* __restrict__ Gw,
    const float* __restrict__ Fw, const float* __restrict__ gx,
    float4* __restrict__ ws_state) {
  extern __shared__ char smem[];
  const int tid = threadIdx.x, l = tid & 63, w = tid >> 6;
  const int lr = l & 15, lg4 = l >> 4;
  int u = (blockIdx.x & 7) * (NUNITS / 8) + (blockIdx.x >> 3);
  const int b = u / (YGRP * NH);
  const int r0 = u % (YGRP * NH);
  const int yg = r0 / NH, nh = r0 % NH;
  const int ybase = yg * 64 + w * 16;
  const int nbase = nh * (NQ / NH);

  // ---- W fragments into registers (48 frags -> AGPRs) ----
  bf16x8 wU[16], wG[16], wF[16];
  {
    int y = ybase + lr; if (y >= YQ) y = YQ - 1;
    if constexpr (FULL) {
      const char* p0 = ws_w + ((size_t)y * DQ + lg4 * 8) * 2;
#pragma unroll
      for (int kk = 0; kk < 16; ++kk) {
        wU[kk] = *(const bf16x8*)(p0 + kk * 64);
        wG[kk] = *(const bf16x8*)(p0 + (size_t)YQ * 1024 + kk * 64);
        wF[kk] = *(const bf16x8*)(p0 + (size_t)YQ * 2048 + kk * 64);
      }
    } else {
      const float* pu = Uw + (size_t)y * DQ + lg4 * 8;
      const float* pg = Gw + (size_t)y * DQ + lg4 * 8;
      const float* pf = Fw + (size_t)y * DQ + lg4 * 8;
#pragma unroll
      for (int kk = 0; kk < 16; ++kk) {
        wU[kk] = pack8(*(const float4*)(pu + kk * 32), *(const float4*)(pu + kk * 32 + 4));
        wG[kk] = pack8(*(const float4*)(pg + kk * 32), *(const float4*)(pg + kk * 32 + 4));
        wF[kk] = pack8(*(const float4*)(pf + kk * 32), *(const float4*)(pf + kk * 32 + 4));
      }
    }
  }

  float lU = 0.f, aU = 0.f, lG = 0.f, aG = 0.f;

  if constexpr (FULL) {
    // Anti-phase skew: co-resident blocks (~bid and bid+256 under fill-first
    // dispatch) get opposite parity; odd layer sleeps ~1792 cy ≈ half a
    // chunk-window so its read phase lands under the peer's MFMA phase.
    if ((blockIdx.x >> 8) & 1) __builtin_amdgcn_s_sleep(28);

    *(float2*)(smem + GXOFF + tid * 8) = *(const float2*)(gx + b * NQ + nbase + tid * 2);
    const char* xb = ws_x2 + (((size_t)(b * 128 + nh * 32)) << 14);
    auto stage = [&](int c) {
      const char* src = xb + ((size_t)c << 14);
      char* lb = smem + (c & 3) * 16384;
#pragma unroll
      for (int j = 0; j < 4; ++j) {
        int s = w * 4 + j;
        gl_lds16(src + s * 1024 + l * 16, lb + s * 1024);
      }
    };
    auto mfma_only = [&](int c, f32x4& sU, f32x4& sG, f32x4& sF) {
      const char* ab = smem + (c & 3) * 16384 + l * 16;
#pragma unroll
      for (int r = 0; r < 4; ++r) { sU[r] = 0.f; sG[r] = 0.f; sF[r] = 0.f; }
      __builtin_amdgcn_s_setprio(1);
#pragma unroll
      for (int kk = 0; kk < 16; ++kk) {
        bf16x8 a = *(const bf16x8*)(ab + kk * 1024);
        sU = __builtin_amdgcn_mfma_f32_16x16x32_bf16(a, wU[kk], sU, 0, 0, 0);
        sG = __builtin_amdgcn_mfma_f32_16x16x32_bf16(a, wG[kk], sG, 0, 0, 0);
        sF = __builtin_amdgcn_mfma_f32_16x16x32_bf16(a, wF[kk], sF, 0, 0, 0);
      }
      __builtin_amdgcn_s_setprio(0);
    };
    auto tail = [&](int c, const f32x4& sU, const f32x4& sG, const f32x4& sF) {
      float4 gxv = *(const float4*)(smem + GXOFF + c * 64 + lg4 * 16);
      float gv[4] = {gxv.x, gxv.y, gxv.z, gxv.w};
#pragma unroll
      for (int r = 0; r < 4; ++r) {
        float eu = __builtin_amdgcn_exp2f(sU[r] * L2E);
        lU += eu; aU = fmaf(eu, sF[r], aU);
        float eg = __builtin_amdgcn_exp2f(sG[r] * L2E);
        lG += eg; aG = fmaf(eg, gv[r], aG);
      }
    };

    __syncthreads();                 // drains vmcnt: clean baseline
    stage(0); stage(1);              // outstanding {0,1}
    asm volatile("s_waitcnt vmcnt(4)" ::: "memory");   // chunk0 done (this wave)
    __builtin_amdgcn_s_barrier();                      // chunk0 done (all waves)

    f32x4 pU, pG, pF, qU, qG, qF;
    mfma_only(0, pU, pG, pF);        // outstanding {1}

#pragma unroll 1
    for (int cp = 0; cp < 15; ++cp) {
      const int c0 = 2 * cp;
      stage(c0 + 2); stage(c0 + 3);                    // outstanding {c0+1,c0+2,c0+3}
      asm volatile("s_waitcnt vmcnt(8)" ::: "memory"); // c0+1 done (this wave)
      __builtin_amdgcn_sched_barrier(0);
      __builtin_amdgcn_s_barrier();                    // c0+1 done (all waves)
      mfma_only(c0 + 1, qU, qG, qF);
      tail(c0, pU, pG, pF);                            // overlaps the MFMAs above
      asm volatile("s_waitcnt vmcnt(4)" ::: "memory"); // c0+2 done (this wave)
      __builtin_amdgcn_sched_barrier(0);
      __builtin_amdgcn_s_barrier();                    // c0+2 done (all waves)
      mfma_only(c0 + 2, pU, pG, pF);
      tail(c0 + 1, qU, qG, qF);
    }
    // entry here: P = scores(30); chunk 31 staged, outstanding {31}
    asm volatile("s_waitcnt vmcnt(0)" ::: "memory");
    __builtin_amdgcn_sched_barrier(0);
    __builtin_amdgcn_s_barrier();
    mfma_only(31, qU, qG, qF);
    tail(30, pU, pG, pF);
    tail(31, qU, qG, qF);
  } else {
    const float* gxb = gx + b * NQ + nbase + lg4 * 4;
    for (int c = 0; c < NCHQ; ++c) {
      __syncthreads();
#pragma unroll
      for (int j = 0; j < 4; ++j) {
        int slot = j * 256 + tid;                  // 1024 slots * 16B = 16KB
        int kk = slot >> 6, l2 = slot & 63;
        int row = l2 & 15, g4 = l2 >> 4;
        const float* g = x + ((size_t)(b * NQ + nbase + c * 16 + row)) * DQ
                       + kk * 32 + g4 * 8;
        *(bf16x8*)(smem + slot * 16) = pack8(*(const float4*)g, *(const float4*)(g + 4));
      }
      __syncthreads();
      const char* ab = smem + l * 16;
      f32x4 sU = {0.f, 0.f, 0.f, 0.f}, sG = sU, sF = sU;
#pragma unroll
      for (int kk = 0; kk < 16; ++kk) {
        bf16x8 a = *(const bf16x8*)(ab + kk * 1024);
        sU = __builtin_amdgcn_mfma_f32_16x16x32_bf16(a, wU[kk], sU, 0, 0, 0);
        sG = __builtin_amdgcn_mfma_f32_16x16x32_bf16(a, wG[kk], sG, 0, 0, 0);
        sF = __builtin_amdgcn_mfma_f32_16x16x32_bf16(a, wF[kk], sF, 0, 0, 0);
      }
      float4 gxv = *(const float4*)(gxb + c * 16);
      float gv[4] = {gxv.x, gxv.y, gxv.z, gxv.w};
#pragma unroll
      for (int r = 0; r < 4; ++r) {
        float eu = __builtin_amdgcn_exp2f(sU[r] * L2E);
        lU += eu; aU = fmaf(eu, sF[r], aU);
        float eg = __builtin_amdgcn_exp2f(sG[r] * L2E);
        lG += eg; aG = fmaf(eg, gv[r], aG);
      }
    }
  }

  // ---- additive lane-group merge ----
#pragma unroll
  for (int d = 16; d < 64; d <<= 1) {
    lU += __shfl_xor(lU, d); aU += __shfl_xor(aU, d);
    lG += __shfl_xor(lG, d); aG += __shfl_xor(aG, d);
  }

  int y = ybase + lr;
  if (lg4 == 0 && y < YQ) {
    float4 st; st.x = lU; st.y = aU; st.z = lG; st.w = aG;
    ws_state[(size_t)(b * NH + nh) * YQ + y] = st;
  }
}

// ---- merge quarters + epilogue + loss partials ----
__global__ __launch_bounds__(256) void merge_kernel(
    const float4* __restrict__ ws_state, const float* __restrict__ fb,
    const float* __restrict__ gate_b, const float* __restrict__ yflow,
    const float* __restrict__ target, float* __restrict__ out_y,
    float* __restrict__ loss_part) {
  __shared__ float sb[256];
  int t = blockIdx.x * 256 + threadIdx.x;
  float lt = 0.f;
  if (t < BQ * YQ) {
    int b = t / YQ, y = t % YQ;
    float lU = 0.f, aU = 0.f, lG = 0.f, aG = 0.f;
#pragma unroll
    for (int nh = 0; nh < NH; ++nh) {
      float4 s = ws_state[(size_t)(b * NH + nh) * YQ + y];
      lU += s.x; aU += s.y; lG += s.z; aG += s.w;
    }
    float gate = tanhf(aG / lG + gate_b[0]);
    float yv = aU / lU + fb[y] + yflow[t] * gate;
    out_y[t] = yv;
    float tg = target[t];
    lt = fmaxf(yv, 0.f) + log1pf(__expf(-fabsf(yv))) - yv * tg;
  }
  sb[threadIdx.x] = lt;
  __syncthreads();
  for (int st = 128; st > 0; st >>= 1) {
    if (threadIdx.x < st) sb[threadIdx.x] += sb[threadIdx.x + st];
    __syncthreads();
  }
  if (threadIdx.x == 0) loss_part[blockIdx.x] = sb[0];
}

__global__ __launch_bounds__(256) void loss_kernel(const float* __restrict__ lp,
                                                   float* __restrict__ out) {
  __shared__ float sb[256];
  float s = (threadIdx.x < NLP) ? lp[threadIdx.x] : 0.f;
  sb[threadIdx.x] = s;
  __syncthreads();
  for (int st = 128; st > 0; st >>= 1) {
    if (threadIdx.x < st) sb[threadIdx.x] += sb[threadIdx.x + st];
    __syncthreads();
  }
  if (threadIdx.x == 0) out[BQ * YQ] = sb[0] / (float)(BQ * YQ);
}

extern "C" void kernel_launch(void* const* d_in, const int* in_sizes, int n_in,
                              void* d_out, int out_size, void* d_ws, size_t ws_size,
                              hipStream_t stream) {
  const float* x      = (const float*)d_in[0];
  const float* target = (const float*)d_in[1];
  const float* yflow  = (const float*)d_in[2];
  const float* Uw     = (const float*)d_in[3];
  const float* Gw     = (const float*)d_in[4];
  const float* Fw     = (const float*)d_in[5];
  const float* fb     = (const float*)d_in[6];
  const float* gw     = (const float*)d_in[7];
  const float* gb     = (const float*)d_in[8];
  float* out = (float*)d_out;
  char* ws = (char*)d_ws;

  const size_t xbytes  = (size_t)BQ * NQ * DQ * 2;          // 8 MB frag-ordered
  const size_t wbytes  = (size_t)3 * YQ * DQ * 2;           // ~27.4 MB
  const size_t gxbytes = (size_t)BQ * NQ * 4;               // 32 KB
  const size_t stbytes = (size_t)BQ * NH * YQ * 16;         // ~2.3 MB
  const size_t lpbytes = (size_t)NLP * 4;
  const bool full = ws_size >= xbytes + wbytes + gxbytes + stbytes + lpbytes;

  char* ws_x2; char* ws_w; float* gxp; float4* stp; float* lp;
  if (full) {
    ws_x2 = ws; ws_w = ws + xbytes;
    gxp = (float*)(ws + xbytes + wbytes);
    stp = (float4*)(ws + xbytes + wbytes + gxbytes);
    lp  = (float*)(ws + xbytes + wbytes + gxbytes + stbytes);
  } else {
    ws_x2 = nullptr; ws_w = nullptr;
    gxp = (float*)ws;
    stp = (float4*)(ws + gxbytes);
    lp  = (float*)(ws + gxbytes + stbytes);
  }

  (void)hipFuncSetAttribute(reinterpret_cast<const void*>(&fused_kernel<true>),
                            hipFuncAttributeMaxDynamicSharedMemorySize, 67584);
  (void)hipFuncSetAttribute(reinterpret_cast<const void*>(&fused_kernel<false>),
                            hipFuncAttributeMaxDynamicSharedMemorySize, 16384);

  if (full) {
    prep_xfrag<<<dim3(BQ * 128), 256, 0, stream>>>(x, gw, ws_x2, gxp);
    prep_w<<<dim3((3 * YQ + 3) / 4), 256, 0, stream>>>(Uw, Gw, Fw, ws_w);
    fused_kernel<true ><<<dim3(NUNITS), 256, 67584, stream>>>(
        x, ws_x2, ws_w, Uw, Gw, Fw, gxp, stp);
  } else {
    prep_gx<<<dim3(2048), 256, 0, stream>>>(x, gw, gxp);
    fused_kernel<false><<<dim3(NUNITS), 256, 16384, stream>>>(
        x, ws_x2, ws_w, Uw, Gw, Fw, gxp, stp);
  }
  merge_kernel<<<dim3(NLP), 256, 0, stream>>>(stp, fb, gb, yflow, target, out, lp);
  loss_kernel<<<1, 256, 0, stream>>>(lp, out);
}